// Round 13
// baseline (99.283 us; speedup 1.0000x reference)
//
#include <hip/hip_runtime.h>
#include <stdint.h>

#define NN 8192
#define NE 8192
#define DIM 256
#define NW 128   // 64-bit words per adjacency row (8192 bits)
#define HCAP 64  // max common neighbors; worst case i==j -> deg_max ~55
#define TE 32    // edges per block (fused)

typedef short bf16x8 __attribute__((ext_vector_type(8)));
typedef float f32x4 __attribute__((ext_vector_type(4)));

__device__ __forceinline__ unsigned short f2bf(float f) {
  uint32_t u = __builtin_bit_cast(uint32_t, f);
  u += 0x7fffu + ((u >> 16) & 1u);   // round-to-nearest-even
  return (unsigned short)(u >> 16);
}
__device__ __forceinline__ float bf2f(unsigned short h) {
  uint32_t u = ((uint32_t)h) << 16;
  return __builtin_bit_cast(float, u);
}

// ============ setup: weight transpose (blocks 0..1535) + endpoint rowlist ==
__global__ __launch_bounds__(256) void setup_kernel(
    const int* __restrict__ tar,
    const float* __restrict__ W1c, const float* __restrict__ W2c,
    const float* __restrict__ W1j, const float* __restrict__ W2j,
    const float* __restrict__ Wl1, const float* __restrict__ Wl2,
    unsigned short* __restrict__ Wt,
    int* __restrict__ rowlist,    // [8192]
    int* __restrict__ nflag) {    // [1]
  const int blk = blockIdx.x;
  if (blk < 1536) {
    // Wt[w][n][k] = W[w][k][n]: coalesced read (consecutive n = tid),
    // scattered 2B writes absorbed by L2.
    const float* Ws[6] = {W1c, W2c, W1j, W2j, Wl1, Wl2};
    const int w = blk >> 8;
    const int k = blk & 255;
    const int n = threadIdx.x;
    Wt[w * 65536 + n * DIM + k] = f2bf(Ws[w][k * DIM + n]);
  } else {
    // one block: build bitmask of endpoint rows, then compact to rowlist
    __shared__ uint32_t lmask[256];  // 8192 bits; thread t owns rows 32t..32t+31
    __shared__ int cnt;
    const int tid = threadIdx.x;
    lmask[tid] = 0u;
    if (tid == 0) cnt = 0;
    __syncthreads();
    for (int i = tid; i < 2 * NE; i += 256) {
      const int r = tar[i];
      atomicOr(&lmask[r >> 5], 1u << (r & 31));
    }
    __syncthreads();
    uint32_t m = lmask[tid];
    int base = atomicAdd(&cnt, __popc(m));
    while (m) {
      int b = __builtin_ctz(m);
      m &= m - 1;
      rowlist[base++] = tid * 32 + b;
    }
    __syncthreads();
    if (tid == 0) nflag[0] = cnt;
  }
}

// ============ pack: one endpoint row per wave, 4-deep float4 pipeline ====
// Bit layout: seg s of row r: lane l loads float4 at cols s*256+4l..4l+3;
// ballot(comp q) -> bits[r*128 + s*4 + q], bit l <-> col s*256+4l+q.
__global__ __launch_bounds__(256) void pack_kernel(
    const float* __restrict__ adj,
    const int* __restrict__ rowlist,
    const int* __restrict__ nflag,
    unsigned long long* __restrict__ bits) {
  const int wv = blockIdx.x * 4 + (threadIdx.x >> 6);  // 0..8191
  if (wv >= nflag[0]) return;
  const int row = rowlist[wv];            // wave-uniform (SGPR)
  const float4* __restrict__ adjv = (const float4*)adj + (size_t)row * 2048;
  unsigned long long* __restrict__ pb = bits + (size_t)row * NW;
  const int lane = threadIdx.x & 63;
#pragma unroll 2
  for (int s = 0; s < 32; s += 4) {
    float4 v0 = adjv[(s + 0) * 64 + lane];
    float4 v1 = adjv[(s + 1) * 64 + lane];
    float4 v2 = adjv[(s + 2) * 64 + lane];
    float4 v3 = adjv[(s + 3) * 64 + lane];
    unsigned long long m00 = __ballot(v0.x != 0.0f);
    unsigned long long m01 = __ballot(v0.y != 0.0f);
    unsigned long long m02 = __ballot(v0.z != 0.0f);
    unsigned long long m03 = __ballot(v0.w != 0.0f);
    unsigned long long m10 = __ballot(v1.x != 0.0f);
    unsigned long long m11 = __ballot(v1.y != 0.0f);
    unsigned long long m12 = __ballot(v1.z != 0.0f);
    unsigned long long m13 = __ballot(v1.w != 0.0f);
    unsigned long long m20 = __ballot(v2.x != 0.0f);
    unsigned long long m21 = __ballot(v2.y != 0.0f);
    unsigned long long m22 = __ballot(v2.z != 0.0f);
    unsigned long long m23 = __ballot(v2.w != 0.0f);
    unsigned long long m30 = __ballot(v3.x != 0.0f);
    unsigned long long m31 = __ballot(v3.y != 0.0f);
    unsigned long long m32 = __ballot(v3.z != 0.0f);
    unsigned long long m33 = __ballot(v3.w != 0.0f);
    if (lane == 0) {
      unsigned long long* p = pb + s * 4;
      p[0]  = m00; p[1]  = m01; p[2]  = m02; p[3]  = m03;
      p[4]  = m10; p[5]  = m11; p[6]  = m12; p[7]  = m13;
      p[8]  = m20; p[9]  = m21; p[10] = m22; p[11] = m23;
      p[12] = m30; p[13] = m31; p[14] = m32; p[15] = m33;
    }
  }
}

// ================= fused: 7-barrier pipeline (R9 verbatim) ========
// Block: 1024 threads = 16 waves, TE=32 edges, 256 blocks (1/CU).
// A-frag: row = lane&15, k = (lane>>4)*8 + j
// B-frag: col = lane&15, k = (lane>>4)*8 + j  (register-resident, prefetched)
// C/D:    col = lane&15, row = (lane>>4)*4 + reg   (m89-verified)

#define LDP 264  // 256 + 8 bf16 pad (row stride 528 B, 2-way bank alias = free)

__device__ __forceinline__ void load_w16(const unsigned short* __restrict__ Wt,
                                         bf16x8 w[8], int lane, int wave) {
  const int lr = lane & 15;
  const int kl = (lane >> 4) * 8;
  const int n0 = wave * 16;
#pragma unroll
  for (int kk = 0; kk < 8; ++kk)
    w[kk] = *(const bf16x8*)(Wt + (size_t)(n0 + lr) * DIM + kk * 32 + kl);
}

__device__ __forceinline__ void gemm16(const unsigned short (*src)[LDP],
                                       const bf16x8 w[8],
                                       f32x4 acc[2], int lane) {
  const int lr = lane & 15;
  const int kl = (lane >> 4) * 8;
#pragma unroll
  for (int kk = 0; kk < 8; ++kk) {
    const int k0 = kk * 32 + kl;
    bf16x8 a0 = *(const bf16x8*)(&src[lr][k0]);
    bf16x8 a1 = *(const bf16x8*)(&src[16 + lr][k0]);
    acc[0] = __builtin_amdgcn_mfma_f32_16x16x32_bf16(a0, w[kk], acc[0], 0, 0, 0);
    acc[1] = __builtin_amdgcn_mfma_f32_16x16x32_bf16(a1, w[kk], acc[1], 0, 0, 0);
  }
}

__device__ __forceinline__ void epilogue16(f32x4 acc[2], float bb, bool relu,
                                           unsigned short (*dst)[LDP],
                                           int lane, int wave) {
  const int lc = lane & 15;
  const int rg = (lane >> 4) * 4;
  const int col = wave * 16 + lc;
#pragma unroll
  for (int m = 0; m < 2; ++m)
#pragma unroll
    for (int q = 0; q < 4; ++q) {
      float v = acc[m][q] + bb;
      if (relu) v = fmaxf(v, 0.f);
      dst[m * 16 + rg + q][col] = f2bf(v);
    }
}

__global__ __launch_bounds__(1024) void fused_kernel(
    const float* __restrict__ x,
    const unsigned long long* __restrict__ bits,
    const int* __restrict__ tar,
    const unsigned short* __restrict__ Wt,
    const float* __restrict__ b1c, const float* __restrict__ b2c,
    const float* __restrict__ b1j, const float* __restrict__ b2j,
    const float* __restrict__ bl1, const float* __restrict__ bl2,
    const float* __restrict__ Wout, const float* __restrict__ bout,
    float* __restrict__ out) {
  __shared__ unsigned short lA[TE][LDP];  // xcn -> h
  __shared__ unsigned short lB[TE][LDP];  // U2 -> h2
  __shared__ unsigned short lC[TE][LDP];  // xixj -> U1
  __shared__ int hits[TE][HCAP];
  __shared__ int nh[TE];
  __shared__ float sPart[16][TE];         // per-wave GEMV partials

  const int tid = threadIdx.x;
  const int lane = tid & 63;
  const int wave = tid >> 6;  // 0..15
  const int e0 = blockIdx.x * TE;

  // ---- per-lane constant preloads ----
  const int lc = lane & 15;
  const int c0 = wave * 16 + lc;
  const float vb1c = b1c[c0];
  const float vb1j = b1j[c0];
  const float vb2 = b2c[c0] + b2j[c0];
  const float vbl1 = bl1[c0];
  const float vbl2 = bl2[c0];
  const float vwout = Wout[c0];
  const float vbout = bout[0];

  if (tid < TE) nh[tid] = 0;

  // ---- (a) bits words -> regs (32 thr/edge, 4 words each endpoint) ----
  const int e_a = tid >> 5;
  const int t32 = tid & 31;
  unsigned long long bw_i[4], bw_j[4];
  {
    const int ia = tar[e0 + e_a];
    const int ja = tar[NE + e0 + e_a];
    const unsigned long long* bi = bits + (size_t)ia * NW + t32 * 4;
    const unsigned long long* bj = bits + (size_t)ja * NW + t32 * 4;
#pragma unroll
    for (int q = 0; q < 4; ++q) { bw_i[q] = bi[q]; bw_j[q] = bj[q]; }
  }

  // ---- (b) xixj -> lC ; then issue W1j/W1c prefetch ----
  {
    const int col = tid & 255;
    const int sub = tid >> 8;  // 0..3 -> 8 edges each
    float vi[8], vj[8];
#pragma unroll
    for (int p = 0; p < 8; ++p) {
      const int e = sub * 8 + p;
      vi[p] = x[(size_t)tar[e0 + e] * DIM + col];
      vj[p] = x[(size_t)tar[NE + e0 + e] * DIM + col];
    }
#pragma unroll
    for (int p = 0; p < 8; ++p)
      lC[sub * 8 + p][col] = f2bf(vi[p] * vj[p]);
  }
  bf16x8 wX[8], wY[8];
  load_w16(Wt + 2 * 65536, wX, lane, wave);  // W1j (used P3)
  load_w16(Wt + 0 * 65536, wY, lane, wave);  // W1c (used P4)
  __syncthreads();  // [1] nh zeroed; lC ready

  // ---- (c) intersect (pure VALU + LDS atomics; weight loads in flight) ----
#pragma unroll
  for (int q = 0; q < 4; ++q) {
    unsigned long long m = bw_i[q] & bw_j[q];
    const int base = t32 << 8;
    while (m) {
      int b = __builtin_ctzll(m);
      m &= m - 1;
      int idx = atomicAdd(&nh[e_a], 1);
      if (idx < HCAP) hits[e_a][idx] = base + (b << 2) + q;  // node id
    }
  }
  __syncthreads();  // [2] hits ready

  f32x4 acc[2];
  const f32x4 z4 = {0.f, 0.f, 0.f, 0.f};

  // ---- P3: xcn gathers -> lA  ∥  U2 = relu(xixj @ W1j + b1j) -> lB ----
  {
    const int col = tid & 255;
    const int sub = tid >> 8;
    float xc[8];
#pragma unroll
    for (int p = 0; p < 8; ++p) {
      const int e = sub * 8 + p;
      const int n = nh[e] < HCAP ? nh[e] : HCAP;
      float s = 0.f;
      for (int h = 0; h < n; ++h)
        s += x[(size_t)hits[e][h] * DIM + col];
      xc[p] = s;
    }
    acc[0] = z4; acc[1] = z4;
    gemm16(lC, wX, acc, lane);                 // U2 (lC = xixj)
    load_w16(Wt + 1 * 65536, wX, lane, wave);  // reload wX = W2c
    epilogue16(acc, vb1j, true, lB, lane, wave);
#pragma unroll
    for (int p = 0; p < 8; ++p)
      lA[sub * 8 + p][col] = f2bf(xc[p]);
  }
  __syncthreads();  // [3] lA = xcn, lB = U2

  // ---- P4: U1 = relu(xcn @ W1c + b1c) -> lC ; reload wY = W2j ----
  acc[0] = z4; acc[1] = z4;
  gemm16(lA, wY, acc, lane);
  load_w16(Wt + 3 * 65536, wY, lane, wave);
  epilogue16(acc, vb1c, true, lC, lane, wave);
  __syncthreads();  // [4] lC = U1

  // ---- P5: h = U1@W2c + U2@W2j + b2 -> lA (no relu) ; wX=Wl1, wY=Wl2 ----
  acc[0] = z4; acc[1] = z4;
  gemm16(lC, wX, acc, lane);
  gemm16(lB, wY, acc, lane);
  load_w16(Wt + 4 * 65536, wX, lane, wave);  // Wl1
  load_w16(Wt + 5 * 65536, wY, lane, wave);  // Wl2
  epilogue16(acc, vb2, false, lA, lane, wave);
  __syncthreads();  // [5] lA = h

  // ---- P6: h2 = relu(h @ Wl1 + bl1) -> lB ----
  acc[0] = z4; acc[1] = z4;
  gemm16(lA, wX, acc, lane);
  epilogue16(acc, vbl1, true, lB, lane, wave);
  __syncthreads();  // [6] lB = h2

  // ---- P7: h3 = relu(h2 @ Wl2 + bl2) in regs ; GEMV partial reduce ----
  acc[0] = z4; acc[1] = z4;
  gemm16(lB, wY, acc, lane);
  {
    const int rg = (lane >> 4) * 4;
    float v[2][4];
#pragma unroll
    for (int m = 0; m < 2; ++m)
#pragma unroll
      for (int q = 0; q < 4; ++q) {
        float h3 = fmaxf(acc[m][q] + vbl2, 0.f);
        v[m][q] = h3 * vwout;
      }
#pragma unroll
    for (int o = 1; o < 16; o <<= 1)
#pragma unroll
      for (int m = 0; m < 2; ++m)
#pragma unroll
        for (int q = 0; q < 4; ++q)
          v[m][q] += __shfl_xor(v[m][q], o);
    if (lc == 0) {
#pragma unroll
      for (int m = 0; m < 2; ++m)
#pragma unroll
        for (int q = 0; q < 4; ++q)
          sPart[wave][m * 16 + rg + q] = v[m][q];
    }
  }
  __syncthreads();  // [7] sPart ready

  // ---- final: deterministic 16-way sum ----
  if (tid < TE) {
    float s = 0.f;
#pragma unroll
    for (int w = 0; w < 16; ++w) s += sPart[w][tid];
    out[e0 + tid] = s + vbout;
  }
}

extern "C" void kernel_launch(void* const* d_in, const int* in_sizes, int n_in,
                              void* d_out, int out_size, void* d_ws, size_t ws_size,
                              hipStream_t stream) {
  const float* x    = (const float*)d_in[0];
  const float* adj  = (const float*)d_in[1];
  const int*   tar  = (const int*)d_in[2];
  const float* W1c  = (const float*)d_in[3];
  const float* b1c  = (const float*)d_in[4];
  const float* W2c  = (const float*)d_in[5];
  const float* b2c  = (const float*)d_in[6];
  const float* W1j  = (const float*)d_in[7];
  const float* b1j  = (const float*)d_in[8];
  const float* W2j  = (const float*)d_in[9];
  const float* b2j  = (const float*)d_in[10];
  const float* Wl1  = (const float*)d_in[11];
  const float* bl1  = (const float*)d_in[12];
  const float* Wl2  = (const float*)d_in[13];
  const float* bl2  = (const float*)d_in[14];
  const float* Wout = (const float*)d_in[15];
  const float* bout = (const float*)d_in[16];

  char* ws = (char*)d_ws;
  unsigned short*     Wt      = (unsigned short*)(ws);                  // 768 KB
  unsigned long long* bits    = (unsigned long long*)(ws + (1u << 20)); // 8 MB
  int*                rowlist = (int*)(ws + (9u << 20));                // 32 KB
  int*                nflag   = (int*)(ws + (9u << 20) + 32768);        // 4 B

  setup_kernel<<<1537, 256, 0, stream>>>(tar, W1c, W2c, W1j, W2j, Wl1, Wl2,
                                         Wt, rowlist, nflag);

  pack_kernel<<<2048, 256, 0, stream>>>(adj, rowlist, nflag, bits);

  fused_kernel<<<NE / TE, 1024, 0, stream>>>(x, bits, tar, Wt, b1c, b2c, b1j,
                                             b2j, bl1, bl2, Wout, bout,
                                             (float*)d_out);
}

// Round 14
// 81.567 us; speedup vs baseline: 1.2172x; 1.2172x over previous
//
#include <hip/hip_runtime.h>
#include <stdint.h>

#define NN 8192
#define NE 8192
#define DIM 256
#define NW 128   // 64-bit words per adjacency row (8192 bits)
#define HCAP 64  // max common neighbors; worst case i==j -> deg_max ~55
#define TE 32    // edges per block (fused)

typedef short bf16x8 __attribute__((ext_vector_type(8)));
typedef float f32x4 __attribute__((ext_vector_type(4)));

__device__ __forceinline__ unsigned short f2bf(float f) {
  uint32_t u = __builtin_bit_cast(uint32_t, f);
  u += 0x7fffu + ((u >> 16) & 1u);   // round-to-nearest-even
  return (unsigned short)(u >> 16);
}
__device__ __forceinline__ float bf2f(unsigned short h) {
  uint32_t u = ((uint32_t)h) << 16;
  return __builtin_bit_cast(float, u);
}

// ==== prep: pack (blocks 0..4095) + transpose (4096..5631) + xij (5632..6143)
// Pack bit layout: task t covers row r = t>>5, segment s = t&31 (256 cols).
// Lane l loads float4 at cols s*256 + 4l .. 4l+3. ballot(component q) ->
// word bits[r*128 + s*4 + q], bit l  <->  col = s*256 + 4*l + q.
__global__ __launch_bounds__(256) void prep_kernel(
    const float* __restrict__ adj,
    const float* __restrict__ x,
    const int* __restrict__ tar,
    const float* __restrict__ W1c, const float* __restrict__ W2c,
    const float* __restrict__ W1j, const float* __restrict__ W2j,
    const float* __restrict__ Wl1, const float* __restrict__ Wl2,
    unsigned short* __restrict__ Wt,
    unsigned long long* __restrict__ bits,
    unsigned short* __restrict__ xij) {
  const int blk = blockIdx.x;
  if (blk < 4096) {
    // ---- adj pack: R7-verbatim 4-deep strided float4 pipeline ----
    const float4* __restrict__ adjv = (const float4*)adj;
    const int lane = threadIdx.x & 63;
    const int wv = blk * 4 + (threadIdx.x >> 6);
    const int nwv = 4096 * 4;
    const int total = NN * 32;  // float4-tasks
    for (int t = 4 * wv; t < total; t += 4 * nwv) {
      float4 v0 = adjv[(size_t)((t + 0) >> 5) * 2048 + ((t + 0) & 31) * 64 + lane];
      float4 v1 = adjv[(size_t)((t + 1) >> 5) * 2048 + ((t + 1) & 31) * 64 + lane];
      float4 v2 = adjv[(size_t)((t + 2) >> 5) * 2048 + ((t + 2) & 31) * 64 + lane];
      float4 v3 = adjv[(size_t)((t + 3) >> 5) * 2048 + ((t + 3) & 31) * 64 + lane];
      unsigned long long m00 = __ballot(v0.x != 0.0f);
      unsigned long long m01 = __ballot(v0.y != 0.0f);
      unsigned long long m02 = __ballot(v0.z != 0.0f);
      unsigned long long m03 = __ballot(v0.w != 0.0f);
      unsigned long long m10 = __ballot(v1.x != 0.0f);
      unsigned long long m11 = __ballot(v1.y != 0.0f);
      unsigned long long m12 = __ballot(v1.z != 0.0f);
      unsigned long long m13 = __ballot(v1.w != 0.0f);
      unsigned long long m20 = __ballot(v2.x != 0.0f);
      unsigned long long m21 = __ballot(v2.y != 0.0f);
      unsigned long long m22 = __ballot(v2.z != 0.0f);
      unsigned long long m23 = __ballot(v2.w != 0.0f);
      unsigned long long m30 = __ballot(v3.x != 0.0f);
      unsigned long long m31 = __ballot(v3.y != 0.0f);
      unsigned long long m32 = __ballot(v3.z != 0.0f);
      unsigned long long m33 = __ballot(v3.w != 0.0f);
      if (lane == 0) {
        unsigned long long* p = bits + (size_t)(t >> 5) * NW + (t & 31) * 4;
        p[0]  = m00; p[1]  = m01; p[2]  = m02; p[3]  = m03;
        p[4]  = m10; p[5]  = m11; p[6]  = m12; p[7]  = m13;
        p[8]  = m20; p[9]  = m21; p[10] = m22; p[11] = m23;
        p[12] = m30; p[13] = m31; p[14] = m32; p[15] = m33;
      }
    }
  } else if (blk < 5632) {
    // ---- weight transpose: Wt[w][n][k] = W[w][k][n], coalesced read ----
    const float* Ws[6] = {W1c, W2c, W1j, W2j, Wl1, Wl2};
    const int b = blk - 4096;
    const int w = b >> 8;
    const int k = b & 255;
    const int n = threadIdx.x;
    Wt[w * 65536 + n * DIM + k] = f2bf(Ws[w][k * DIM + n]);
  } else {
    // ---- xij precompute: 16 edges per block ----
    const int b = blk - 5632;          // 0..511
    const int e0x = b * 16;
    const int col = threadIdx.x;
    float vi[16], vj[16];
#pragma unroll
    for (int p = 0; p < 16; ++p) {
      vi[p] = x[(size_t)tar[e0x + p] * DIM + col];
      vj[p] = x[(size_t)tar[NE + e0x + p] * DIM + col];
    }
#pragma unroll
    for (int p = 0; p < 16; ++p)
      xij[(size_t)(e0x + p) * DIM + col] = f2bf(vi[p] * vj[p]);
  }
}

// ================= fused: 7-barrier pipeline (R9 base, xij precomputed) ====
// Block: 1024 threads = 16 waves, TE=32 edges, 256 blocks (1/CU).
// A-frag: row = lane&15, k = (lane>>4)*8 + j
// B-frag: col = lane&15, k = (lane>>4)*8 + j  (register-resident, prefetched)
// C/D:    col = lane&15, row = (lane>>4)*4 + reg   (m89-verified)

#define LDP 264  // 256 + 8 bf16 pad (row stride 528 B, 2-way bank alias = free)

__device__ __forceinline__ void load_w16(const unsigned short* __restrict__ Wt,
                                         bf16x8 w[8], int lane, int wave) {
  const int lr = lane & 15;
  const int kl = (lane >> 4) * 8;
  const int n0 = wave * 16;
#pragma unroll
  for (int kk = 0; kk < 8; ++kk)
    w[kk] = *(const bf16x8*)(Wt + (size_t)(n0 + lr) * DIM + kk * 32 + kl);
}

__device__ __forceinline__ void gemm16(const unsigned short (*src)[LDP],
                                       const bf16x8 w[8],
                                       f32x4 acc[2], int lane) {
  const int lr = lane & 15;
  const int kl = (lane >> 4) * 8;
#pragma unroll
  for (int kk = 0; kk < 8; ++kk) {
    const int k0 = kk * 32 + kl;
    bf16x8 a0 = *(const bf16x8*)(&src[lr][k0]);
    bf16x8 a1 = *(const bf16x8*)(&src[16 + lr][k0]);
    acc[0] = __builtin_amdgcn_mfma_f32_16x16x32_bf16(a0, w[kk], acc[0], 0, 0, 0);
    acc[1] = __builtin_amdgcn_mfma_f32_16x16x32_bf16(a1, w[kk], acc[1], 0, 0, 0);
  }
}

__device__ __forceinline__ void epilogue16(f32x4 acc[2], float bb, bool relu,
                                           unsigned short (*dst)[LDP],
                                           int lane, int wave) {
  const int lc = lane & 15;
  const int rg = (lane >> 4) * 4;
  const int col = wave * 16 + lc;
#pragma unroll
  for (int m = 0; m < 2; ++m)
#pragma unroll
    for (int q = 0; q < 4; ++q) {
      float v = acc[m][q] + bb;
      if (relu) v = fmaxf(v, 0.f);
      dst[m * 16 + rg + q][col] = f2bf(v);
    }
}

__global__ __launch_bounds__(1024) void fused_kernel(
    const float* __restrict__ x,
    const unsigned long long* __restrict__ bits,
    const int* __restrict__ tar,
    const unsigned short* __restrict__ Wt,
    const unsigned short* __restrict__ xij,
    const float* __restrict__ b1c, const float* __restrict__ b2c,
    const float* __restrict__ b1j, const float* __restrict__ b2j,
    const float* __restrict__ bl1, const float* __restrict__ bl2,
    const float* __restrict__ Wout, const float* __restrict__ bout,
    float* __restrict__ out) {
  __shared__ unsigned short lA[TE][LDP];  // xcn -> h
  __shared__ unsigned short lB[TE][LDP];  // U2 -> h2
  __shared__ unsigned short lC[TE][LDP];  // xixj -> U1
  __shared__ int hits[TE][HCAP];
  __shared__ int nh[TE];
  __shared__ float sPart[16][TE];         // per-wave GEMV partials

  const int tid = threadIdx.x;
  const int lane = tid & 63;
  const int wave = tid >> 6;  // 0..15
  const int e0 = blockIdx.x * TE;

  // ---- per-lane constant preloads ----
  const int lc = lane & 15;
  const int c0 = wave * 16 + lc;
  const float vb1c = b1c[c0];
  const float vb1j = b1j[c0];
  const float vb2 = b2c[c0] + b2j[c0];
  const float vbl1 = bl1[c0];
  const float vbl2 = bl2[c0];
  const float vwout = Wout[c0];
  const float vbout = bout[0];

  if (tid < TE) nh[tid] = 0;

  // ---- (a) bits words -> regs (32 thr/edge, 4 words each endpoint) ----
  const int e_a = tid >> 5;
  const int t32 = tid & 31;
  unsigned long long bw_i[4], bw_j[4];
  {
    const int ia = tar[e0 + e_a];
    const int ja = tar[NE + e0 + e_a];
    const unsigned long long* bi = bits + (size_t)ia * NW + t32 * 4;
    const unsigned long long* bj = bits + (size_t)ja * NW + t32 * 4;
#pragma unroll
    for (int q = 0; q < 4; ++q) { bw_i[q] = bi[q]; bw_j[q] = bj[q]; }
  }

  // ---- (b) xij (precomputed) -> lC, one uint4 per thread ----
  {
    const int e = tid >> 5;         // 0..31
    const int c8 = (tid & 31) * 8;  // 8 bf16
    *(uint4*)(&lC[e][c8]) = *(const uint4*)(xij + (size_t)(e0 + e) * DIM + c8);
  }
  bf16x8 wX[8], wY[8];
  load_w16(Wt + 2 * 65536, wX, lane, wave);  // W1j (used P3)
  load_w16(Wt + 0 * 65536, wY, lane, wave);  // W1c (used P4)
  __syncthreads();  // [1] nh zeroed; lC ready

  // ---- (c) intersect (pure VALU + LDS atomics; weight loads in flight) ----
#pragma unroll
  for (int q = 0; q < 4; ++q) {
    unsigned long long m = bw_i[q] & bw_j[q];
    const int base = t32 << 8;
    while (m) {
      int b = __builtin_ctzll(m);
      m &= m - 1;
      int idx = atomicAdd(&nh[e_a], 1);
      if (idx < HCAP) hits[e_a][idx] = base + (b << 2) + q;  // node id
    }
  }
  __syncthreads();  // [2] hits ready

  f32x4 acc[2];
  const f32x4 z4 = {0.f, 0.f, 0.f, 0.f};

  // ---- P3: xcn gathers -> lA  ∥  U2 = relu(xixj @ W1j + b1j) -> lB ----
  {
    const int col = tid & 255;
    const int sub = tid >> 8;
    float xc[8];
#pragma unroll
    for (int p = 0; p < 8; ++p) {
      const int e = sub * 8 + p;
      const int n = nh[e] < HCAP ? nh[e] : HCAP;
      float s = 0.f;
      for (int h = 0; h < n; ++h)
        s += x[(size_t)hits[e][h] * DIM + col];
      xc[p] = s;
    }
    acc[0] = z4; acc[1] = z4;
    gemm16(lC, wX, acc, lane);                 // U2 (lC = xixj)
    load_w16(Wt + 1 * 65536, wX, lane, wave);  // reload wX = W2c
    epilogue16(acc, vb1j, true, lB, lane, wave);
#pragma unroll
    for (int p = 0; p < 8; ++p)
      lA[sub * 8 + p][col] = f2bf(xc[p]);
  }
  __syncthreads();  // [3] lA = xcn, lB = U2

  // ---- P4: U1 = relu(xcn @ W1c + b1c) -> lC ; reload wY = W2j ----
  acc[0] = z4; acc[1] = z4;
  gemm16(lA, wY, acc, lane);
  load_w16(Wt + 3 * 65536, wY, lane, wave);
  epilogue16(acc, vb1c, true, lC, lane, wave);
  __syncthreads();  // [4] lC = U1

  // ---- P5: h = U1@W2c + U2@W2j + b2 -> lA (no relu) ; wX=Wl1, wY=Wl2 ----
  acc[0] = z4; acc[1] = z4;
  gemm16(lC, wX, acc, lane);
  gemm16(lB, wY, acc, lane);
  load_w16(Wt + 4 * 65536, wX, lane, wave);  // Wl1
  load_w16(Wt + 5 * 65536, wY, lane, wave);  // Wl2
  epilogue16(acc, vb2, false, lA, lane, wave);
  __syncthreads();  // [5] lA = h

  // ---- P6: h2 = relu(h @ Wl1 + bl1) -> lB ----
  acc[0] = z4; acc[1] = z4;
  gemm16(lA, wX, acc, lane);
  epilogue16(acc, vbl1, true, lB, lane, wave);
  __syncthreads();  // [6] lB = h2

  // ---- P7: h3 = relu(h2 @ Wl2 + bl2) in regs ; GEMV partial reduce ----
  acc[0] = z4; acc[1] = z4;
  gemm16(lB, wY, acc, lane);
  {
    const int rg = (lane >> 4) * 4;
    float v[2][4];
#pragma unroll
    for (int m = 0; m < 2; ++m)
#pragma unroll
      for (int q = 0; q < 4; ++q) {
        float h3 = fmaxf(acc[m][q] + vbl2, 0.f);
        v[m][q] = h3 * vwout;
      }
#pragma unroll
    for (int o = 1; o < 16; o <<= 1)
#pragma unroll
      for (int m = 0; m < 2; ++m)
#pragma unroll
        for (int q = 0; q < 4; ++q)
          v[m][q] += __shfl_xor(v[m][q], o);
    if (lc == 0) {
#pragma unroll
      for (int m = 0; m < 2; ++m)
#pragma unroll
        for (int q = 0; q < 4; ++q)
          sPart[wave][m * 16 + rg + q] = v[m][q];
    }
  }
  __syncthreads();  // [7] sPart ready

  // ---- final: deterministic 16-way sum ----
  if (tid < TE) {
    float s = 0.f;
#pragma unroll
    for (int w = 0; w < 16; ++w) s += sPart[w][tid];
    out[e0 + tid] = s + vbout;
  }
}

extern "C" void kernel_launch(void* const* d_in, const int* in_sizes, int n_in,
                              void* d_out, int out_size, void* d_ws, size_t ws_size,
                              hipStream_t stream) {
  const float* x    = (const float*)d_in[0];
  const float* adj  = (const float*)d_in[1];
  const int*   tar  = (const int*)d_in[2];
  const float* W1c  = (const float*)d_in[3];
  const float* b1c  = (const float*)d_in[4];
  const float* W2c  = (const float*)d_in[5];
  const float* b2c  = (const float*)d_in[6];
  const float* W1j  = (const float*)d_in[7];
  const float* b1j  = (const float*)d_in[8];
  const float* W2j  = (const float*)d_in[9];
  const float* b2j  = (const float*)d_in[10];
  const float* Wl1  = (const float*)d_in[11];
  const float* bl1  = (const float*)d_in[12];
  const float* Wl2  = (const float*)d_in[13];
  const float* bl2  = (const float*)d_in[14];
  const float* Wout = (const float*)d_in[15];
  const float* bout = (const float*)d_in[16];

  char* ws = (char*)d_ws;
  unsigned short*     Wt   = (unsigned short*)(ws);                   // 768 KB
  unsigned long long* bits = (unsigned long long*)(ws + (1u << 20));  // 8 MB
  unsigned short*     xij  = (unsigned short*)(ws + (10u << 20));     // 4 MB

  prep_kernel<<<6144, 256, 0, stream>>>(adj, x, tar, W1c, W2c, W1j, W2j, Wl1,
                                        Wl2, Wt, bits, xij);

  fused_kernel<<<NE / TE, 1024, 0, stream>>>(x, bits, tar, Wt, xij, b1c, b2c,
                                             b1j, b2j, bl1, bl2, Wout, bout,
                                             (float*)d_out);
}

// Round 15
// 79.230 us; speedup vs baseline: 1.2531x; 1.0295x over previous
//
#include <hip/hip_runtime.h>
#include <stdint.h>

#define NN 8192
#define NE 8192
#define DIM 256
#define NW 128   // 64-bit words per adjacency row (8192 bits)
#define HCAP 64  // max common neighbors; worst case i==j -> deg_max ~55
#define TE 32    // edges per block (fused)

typedef short bf16x8 __attribute__((ext_vector_type(8)));
typedef float f32x4 __attribute__((ext_vector_type(4)));

__device__ __forceinline__ unsigned short f2bf(float f) {
  uint32_t u = __builtin_bit_cast(uint32_t, f);
  u += 0x7fffu + ((u >> 16) & 1u);   // round-to-nearest-even
  return (unsigned short)(u >> 16);
}
__device__ __forceinline__ float bf2f(unsigned short h) {
  uint32_t u = ((uint32_t)h) << 16;
  return __builtin_bit_cast(float, u);
}

// ============ prep: adj pack (blocks 0..4095) + weight transpose (rest) ====
// Pack bit layout: task t covers row r = t>>5, segment s = t&31 (256 cols).
// Lane l loads float4 at cols s*256 + 4l .. 4l+3. ballot(component q) ->
// word bits[r*128 + s*4 + q], bit l  <->  col = s*256 + 4*l + q.
// Split-mask 8-deep: all 8 loads issued up front (8 KB/wave in flight);
// ballots processed in two groups of 16 masks (32 SGPRs live, as 4-deep).
__global__ __launch_bounds__(256) void prep_kernel(
    const float* __restrict__ adj,
    const float* __restrict__ W1c, const float* __restrict__ W2c,
    const float* __restrict__ W1j, const float* __restrict__ W2j,
    const float* __restrict__ Wl1, const float* __restrict__ Wl2,
    unsigned short* __restrict__ Wt,
    unsigned long long* __restrict__ bits) {
  const int blk = blockIdx.x;
  if (blk < 4096) {
    const float4* __restrict__ adjv = (const float4*)adj;
    const int lane = threadIdx.x & 63;
    const int wv = blk * 4 + (threadIdx.x >> 6);
    const int nwv = 4096 * 4;
    const int total = NN * 32;  // float4-tasks
    for (int t = 8 * wv; t < total; t += 8 * nwv) {
      // t%8==0 -> all 8 tasks within one row: 32 contiguous u64 words
      float4 v0 = adjv[(size_t)((t + 0) >> 5) * 2048 + ((t + 0) & 31) * 64 + lane];
      float4 v1 = adjv[(size_t)((t + 1) >> 5) * 2048 + ((t + 1) & 31) * 64 + lane];
      float4 v2 = adjv[(size_t)((t + 2) >> 5) * 2048 + ((t + 2) & 31) * 64 + lane];
      float4 v3 = adjv[(size_t)((t + 3) >> 5) * 2048 + ((t + 3) & 31) * 64 + lane];
      float4 v4 = adjv[(size_t)((t + 4) >> 5) * 2048 + ((t + 4) & 31) * 64 + lane];
      float4 v5 = adjv[(size_t)((t + 5) >> 5) * 2048 + ((t + 5) & 31) * 64 + lane];
      float4 v6 = adjv[(size_t)((t + 6) >> 5) * 2048 + ((t + 6) & 31) * 64 + lane];
      float4 v7 = adjv[(size_t)((t + 7) >> 5) * 2048 + ((t + 7) & 31) * 64 + lane];
      unsigned long long* p = bits + (size_t)(t >> 5) * NW + (t & 31) * 4;
      // group 1: tasks t..t+3 (waits vmcnt(4); v4..v7 stay in flight)
      {
        unsigned long long m00 = __ballot(v0.x != 0.0f);
        unsigned long long m01 = __ballot(v0.y != 0.0f);
        unsigned long long m02 = __ballot(v0.z != 0.0f);
        unsigned long long m03 = __ballot(v0.w != 0.0f);
        unsigned long long m10 = __ballot(v1.x != 0.0f);
        unsigned long long m11 = __ballot(v1.y != 0.0f);
        unsigned long long m12 = __ballot(v1.z != 0.0f);
        unsigned long long m13 = __ballot(v1.w != 0.0f);
        unsigned long long m20 = __ballot(v2.x != 0.0f);
        unsigned long long m21 = __ballot(v2.y != 0.0f);
        unsigned long long m22 = __ballot(v2.z != 0.0f);
        unsigned long long m23 = __ballot(v2.w != 0.0f);
        unsigned long long m30 = __ballot(v3.x != 0.0f);
        unsigned long long m31 = __ballot(v3.y != 0.0f);
        unsigned long long m32 = __ballot(v3.z != 0.0f);
        unsigned long long m33 = __ballot(v3.w != 0.0f);
        if (lane == 0) {
          p[0]  = m00; p[1]  = m01; p[2]  = m02; p[3]  = m03;
          p[4]  = m10; p[5]  = m11; p[6]  = m12; p[7]  = m13;
          p[8]  = m20; p[9]  = m21; p[10] = m22; p[11] = m23;
          p[12] = m30; p[13] = m31; p[14] = m32; p[15] = m33;
        }
      }
      // group 2: tasks t+4..t+7
      {
        unsigned long long m00 = __ballot(v4.x != 0.0f);
        unsigned long long m01 = __ballot(v4.y != 0.0f);
        unsigned long long m02 = __ballot(v4.z != 0.0f);
        unsigned long long m03 = __ballot(v4.w != 0.0f);
        unsigned long long m10 = __ballot(v5.x != 0.0f);
        unsigned long long m11 = __ballot(v5.y != 0.0f);
        unsigned long long m12 = __ballot(v5.z != 0.0f);
        unsigned long long m13 = __ballot(v5.w != 0.0f);
        unsigned long long m20 = __ballot(v6.x != 0.0f);
        unsigned long long m21 = __ballot(v6.y != 0.0f);
        unsigned long long m22 = __ballot(v6.z != 0.0f);
        unsigned long long m23 = __ballot(v6.w != 0.0f);
        unsigned long long m30 = __ballot(v7.x != 0.0f);
        unsigned long long m31 = __ballot(v7.y != 0.0f);
        unsigned long long m32 = __ballot(v7.z != 0.0f);
        unsigned long long m33 = __ballot(v7.w != 0.0f);
        if (lane == 0) {
          p[16] = m00; p[17] = m01; p[18] = m02; p[19] = m03;
          p[20] = m10; p[21] = m11; p[22] = m12; p[23] = m13;
          p[24] = m20; p[25] = m21; p[26] = m22; p[27] = m23;
          p[28] = m30; p[29] = m31; p[30] = m32; p[31] = m33;
        }
      }
    }
  } else {
    // Wt[w][n][k] = W[w][k][n], bf16 (R7 verbatim)
    const float* Ws[6] = {W1c, W2c, W1j, W2j, Wl1, Wl2};
    const int b = blk - 4096;
    const int w = b >> 8;
    const int n = b & 255;
    const int k = threadIdx.x;
    Wt[w * 65536 + n * DIM + k] = f2bf(Ws[w][k * DIM + n]);
  }
}

// ================= fused: CN intersect + xixj + 6-GEMM chain + GEMV ========
// (R7 verbatim) Block: 1024 threads = 16 waves, TE=32 edges, 256 blocks.
// Each wave owns 16 output cols (1 n-tile) x 2 m-tiles of 16 rows.
// A-frag: row = lane&15, k = (lane>>4)*8 + j
// B-frag: col = lane&15, k = (lane>>4)*8 + j  (register-resident, prefetched)
// C/D:    col = lane&15, row = (lane>>4)*4 + reg   (m89-verified)

#define LDP 264  // 256 + 8 bf16 pad (row stride 528 B, 2-way bank alias = free)

__device__ __forceinline__ void load_w16(const unsigned short* __restrict__ Wt,
                                         bf16x8 w[8], int lane, int wave) {
  const int lr = lane & 15;
  const int kl = (lane >> 4) * 8;
  const int n0 = wave * 16;
#pragma unroll
  for (int kk = 0; kk < 8; ++kk)
    w[kk] = *(const bf16x8*)(Wt + (size_t)(n0 + lr) * DIM + kk * 32 + kl);
}

__device__ __forceinline__ void gemm16(const unsigned short (*src)[LDP],
                                       const bf16x8 w[8],
                                       f32x4 acc[2], int lane) {
  const int lr = lane & 15;
  const int kl = (lane >> 4) * 8;
#pragma unroll
  for (int kk = 0; kk < 8; ++kk) {
    const int k0 = kk * 32 + kl;
    bf16x8 a0 = *(const bf16x8*)(&src[lr][k0]);
    bf16x8 a1 = *(const bf16x8*)(&src[16 + lr][k0]);
    acc[0] = __builtin_amdgcn_mfma_f32_16x16x32_bf16(a0, w[kk], acc[0], 0, 0, 0);
    acc[1] = __builtin_amdgcn_mfma_f32_16x16x32_bf16(a1, w[kk], acc[1], 0, 0, 0);
  }
}

__device__ __forceinline__ void epilogue16(f32x4 acc[2], float bb, bool relu,
                                           unsigned short (*dst)[LDP],
                                           int lane, int wave) {
  const int lc = lane & 15;
  const int rg = (lane >> 4) * 4;
  const int col = wave * 16 + lc;
#pragma unroll
  for (int m = 0; m < 2; ++m)
#pragma unroll
    for (int q = 0; q < 4; ++q) {
      float v = acc[m][q] + bb;
      if (relu) v = fmaxf(v, 0.f);
      dst[m * 16 + rg + q][col] = f2bf(v);
    }
}

__global__ __launch_bounds__(1024) void fused_kernel(
    const float* __restrict__ x,
    const unsigned long long* __restrict__ bits,
    const int* __restrict__ tar,
    const unsigned short* __restrict__ Wt,
    const float* __restrict__ b1c, const float* __restrict__ b2c,
    const float* __restrict__ b1j, const float* __restrict__ b2j,
    const float* __restrict__ bl1, const float* __restrict__ bl2,
    const float* __restrict__ Wout, const float* __restrict__ bout,
    float* __restrict__ out) {
  __shared__ unsigned short lA[TE][LDP];  // xcn -> U2 -> h2
  __shared__ unsigned short lB[TE][LDP];  // U1 -> h -> h3
  __shared__ unsigned short lC[TE][LDP];  // xixj
  __shared__ int hits[TE][HCAP];
  __shared__ int nh[TE];

  const int tid = threadIdx.x;
  const int lane = tid & 63;
  const int wave = tid >> 6;  // 0..15
  const int e0 = blockIdx.x * TE;

  // ---- per-lane constant preloads (biases, Wout) ----
  const int lc = lane & 15;
  const int c0 = wave * 16 + lc;
  const float vb1c = b1c[c0];
  const float vb1j = b1j[c0];
  const float vb2 = b2c[c0] + b2j[c0];
  const float vbl1 = bl1[c0];
  const float vbl2 = bl2[c0];
  const int gpart = tid & 31;  // GEMV: 32 threads/edge, 8 cols each
  float wv[8];
#pragma unroll
  for (int q = 0; q < 8; ++q) wv[q] = Wout[gpart * 8 + q];
  const float vbout = bout[0];

  if (tid < TE) nh[tid] = 0;

  // ---- (a) bits words -> regs (32 thr/edge, 4 words each endpoint) ----
  const int e_a = tid >> 5;
  const int t32 = tid & 31;
  const int ia = tar[e0 + e_a];
  const int ja = tar[NE + e0 + e_a];
  unsigned long long bw_i[4], bw_j[4];
  {
    const unsigned long long* bi = bits + (size_t)ia * NW + t32 * 4;
    const unsigned long long* bj = bits + (size_t)ja * NW + t32 * 4;
#pragma unroll
    for (int q = 0; q < 4; ++q) { bw_i[q] = bi[q]; bw_j[q] = bj[q]; }
  }

  // ---- (b) xixj -> lC (independent; hides (a)'s latency) ----
  {
    const int col = tid & 255;
    const int sub = tid >> 8;  // 0..3 -> 8 edges each
    float vi[8], vj[8];
#pragma unroll
    for (int p = 0; p < 8; ++p) {
      const int e = sub * 8 + p;
      vi[p] = x[(size_t)tar[e0 + e] * DIM + col];
      vj[p] = x[(size_t)tar[NE + e0 + e] * DIM + col];
    }
#pragma unroll
    for (int p = 0; p < 8; ++p)
      lC[sub * 8 + p][col] = f2bf(vi[p] * vj[p]);
  }
  __syncthreads();  // nh zeroed; (a)/(b) loads drained

  // ---- (c) intersect (pure VALU + LDS atomics) ----
  // word w = t32*4+q  ->  base col = t32<<8, node = base + 4*bit + q
#pragma unroll
  for (int q = 0; q < 4; ++q) {
    unsigned long long m = bw_i[q] & bw_j[q];
    const int base = t32 << 8;
    while (m) {
      int b = __builtin_ctzll(m);
      m &= m - 1;
      int idx = atomicAdd(&nh[e_a], 1);
      if (idx < HCAP) hits[e_a][idx] = base + (b << 2) + q;  // node id
    }
  }
  __syncthreads();

  // ---- prefetch S1/S2 weights; xcn gathers -> lA ----
  bf16x8 wX[8], wY[8];
  load_w16(Wt + 0 * 65536, wX, lane, wave);
  load_w16(Wt + 1 * 65536, wY, lane, wave);
  {
    const int col = tid & 255;
    const int sub = tid >> 8;
#pragma unroll
    for (int p = 0; p < 8; ++p) {
      const int e = sub * 8 + p;
      const int n = nh[e] < HCAP ? nh[e] : HCAP;
      float xc = 0.f;
      for (int h = 0; h < n; ++h)
        xc += x[(size_t)hits[e][h] * DIM + col];
      lA[e][col] = f2bf(xc);
    }
  }
  __syncthreads();

  f32x4 acc[2], pAcc[2];
  const f32x4 z4 = {0.f, 0.f, 0.f, 0.f};

  // ---- S1: U1 = relu(xcn @ W1c + b1c) -> lB ; prefetch W1j -> wX ----
  acc[0] = z4; acc[1] = z4;
  gemm16(lA, wX, acc, lane);
  load_w16(Wt + 2 * 65536, wX, lane, wave);
  epilogue16(acc, vb1c, true, lB, lane, wave);
  __syncthreads();

  // ---- S2: pAcc = U1 @ W2c (wY); S3: U2 = relu(xixj @ W1j) -> lA (wX) ----
  pAcc[0] = z4; pAcc[1] = z4;
  gemm16(lB, wY, pAcc, lane);
  load_w16(Wt + 3 * 65536, wY, lane, wave);  // prefetch W2j
  acc[0] = z4; acc[1] = z4;
  gemm16(lC, wX, acc, lane);
  epilogue16(acc, vb1j, true, lA, lane, wave);
  __syncthreads();

  // ---- S4: pAcc += U2 @ W2j (wY); h = pAcc + b2c+b2j -> lB (no relu) ----
  gemm16(lA, wY, pAcc, lane);
  load_w16(Wt + 4 * 65536, wX, lane, wave);  // prefetch Wl1
  {
    const int rg = (lane >> 4) * 4;
    const int col = wave * 16 + lc;
#pragma unroll
    for (int m = 0; m < 2; ++m)
#pragma unroll
      for (int q = 0; q < 4; ++q)
        lB[m * 16 + rg + q][col] = f2bf(pAcc[m][q] + vb2);
  }
  __syncthreads();

  // ---- S5: h2 = relu(h @ Wl1 + bl1) -> lA (wX) ; prefetch Wl2 -> wY ----
  acc[0] = z4; acc[1] = z4;
  gemm16(lB, wX, acc, lane);
  load_w16(Wt + 5 * 65536, wY, lane, wave);
  epilogue16(acc, vbl1, true, lA, lane, wave);
  __syncthreads();

  // ---- S6: h3 = relu(h2 @ Wl2 + bl2) -> lB (wY) ----
  acc[0] = z4; acc[1] = z4;
  gemm16(lA, wY, acc, lane);
  epilogue16(acc, vbl2, true, lB, lane, wave);
  __syncthreads();

  // ---- GEMV: out = h3 @ Wout + bout (32 threads/edge, preloaded Wout) ----
  const int el = tid >> 5;
  float s = 0.f;
#pragma unroll
  for (int q = 0; q < 8; ++q)
    s += bf2f(lB[el][gpart * 8 + q]) * wv[q];
#pragma unroll
  for (int o = 16; o; o >>= 1) s += __shfl_xor(s, o);
  if (gpart == 0) out[e0 + el] = s + vbout;
}

extern "C" void kernel_launch(void* const* d_in, const int* in_sizes, int n_in,
                              void* d_out, int out_size, void* d_ws, size_t ws_size,
                              hipStream_t stream) {
  const float* x    = (const float*)d_in[0];
  const float* adj  = (const float*)d_in[1];
  const int*   tar  = (const int*)d_in[2];
  const float* W1c  = (const float*)d_in[3];
  const float* b1c  = (const float*)d_in[4];
  const float* W2c  = (const float*)d_in[5];
  const float* b2c  = (const float*)d_in[6];
  const float* W1j  = (const float*)d_in[7];
  const float* b1j  = (const float*)d_in[8];
  const float* W2j  = (const float*)d_in[9];
  const float* b2j  = (const float*)d_in[10];
  const float* Wl1  = (const float*)d_in[11];
  const float* bl1  = (const float*)d_in[12];
  const float* Wl2  = (const float*)d_in[13];
  const float* bl2  = (const float*)d_in[14];
  const float* Wout = (const float*)d_in[15];
  const float* bout = (const float*)d_in[16];

  char* ws = (char*)d_ws;
  unsigned short*     Wt   = (unsigned short*)(ws);                  // 768 KB
  unsigned long long* bits = (unsigned long long*)(ws + (1u << 20)); // 8 MB

  prep_kernel<<<4096 + 1536, 256, 0, stream>>>(adj, W1c, W2c, W1j, W2j, Wl1,
                                               Wl2, Wt, bits);

  fused_kernel<<<NE / TE, 1024, 0, stream>>>(x, bits, tar, Wt, b1c, b2c, b1j,
                                             b2j, bl1, bl2, Wout, bout,
                                             (float*)d_out);
}